// Round 25
// baseline (248.513 us; speedup 1.0000x reference)
//
#include <hip/hip_runtime.h>
#include <hip/hip_bf16.h>
#include <cstdint>
#include <math.h>

typedef __bf16 bf16_t;
typedef __attribute__((ext_vector_type(2))) __bf16 bf16x2;
typedef __attribute__((ext_vector_type(4))) __bf16 bf16x4;
typedef __attribute__((ext_vector_type(8))) __bf16 bf16x8;
typedef __attribute__((ext_vector_type(4))) float f32x4;
typedef __attribute__((ext_vector_type(16))) float f32x16;
typedef __attribute__((ext_vector_type(2))) int int2v;
typedef __attribute__((ext_vector_type(4))) int int4v;

#define B_SZ 2
#define S_SZ 2048
#define D_MODEL 1024
#define NUM_HEADS 16
#define HEAD_DIM 64
#define FF_DIM 4096
#define M_ROWS (B_SZ * S_SZ)   // 4096

// exp2-domain scale: 0.125 (1/sqrt(64)) * log2(e)
#define CF 0.180336880f
#define THRC 2.0f

__device__ __forceinline__ float fexp2(float x) { return __builtin_amdgcn_exp2f(x); }

// ---------------------------------------------------------------------------
__device__ __forceinline__ void gload_lds16(const void* g, void* lds) {
    __builtin_amdgcn_global_load_lds(
        (const __attribute__((address_space(1))) void*)(uintptr_t)g,
        (__attribute__((address_space(3))) void*)(uint32_t)(uintptr_t)lds,
        16, 0, 0);
}

__device__ __forceinline__ f32x4 mfma16(bf16x8 a, bf16x8 b, f32x4 c) {
    return __builtin_amdgcn_mfma_f32_16x16x32_bf16(a, b, c, 0, 0, 0);
}
__device__ __forceinline__ f32x16 mfma32(bf16x8 a, bf16x8 b, f32x16 c) {
    return __builtin_amdgcn_mfma_f32_32x32x16_bf16(a, b, c, 0, 0, 0);
}
__device__ __forceinline__ int2v plswap(int a, int b) {
    return __builtin_amdgcn_permlane32_swap(a, b, false, false);
}
__device__ __forceinline__ int packbf(float a, float b) {
    bf16x2 t; t[0] = (bf16_t)a; t[1] = (bf16_t)b;
    return __builtin_bit_cast(int, t);
}

__device__ __forceinline__ int xcd_swz(int lin, int nwg) {
    return (lin & 7) * (nwg >> 3) + (lin >> 3);
}

// ---------------------------------------------------------------------------
// ONE prep launch: blocks [0,4096) square-W transposes, [4096,8192) w1,
// [8192,12288) w2, [12288,24576) the three f32->bf16 input casts.
// ---------------------------------------------------------------------------
__global__ __launch_bounds__(256) void prep_all(
    const float* __restrict__ q, const float* __restrict__ k, const float* __restrict__ v,
    bf16_t* __restrict__ qb, bf16_t* __restrict__ kb, bf16_t* __restrict__ vb,
    const float* __restrict__ wq, const float* __restrict__ wk,
    const float* __restrict__ wv, const float* __restrict__ wo,
    const float* __restrict__ w1, const float* __restrict__ w2,
    bf16_t* __restrict__ wqT, bf16_t* __restrict__ wkT,
    bf16_t* __restrict__ wvT, bf16_t* __restrict__ woT,
    bf16_t* __restrict__ w1T, bf16_t* __restrict__ w2T) {
    __shared__ float t[32][33];
    const int id = blockIdx.x;
    const int tid = threadIdx.x;
    if (id >= 12288) {
        const int t2 = id - 12288;
        const int which = t2 >> 12, blk = t2 & 4095;
        const float* in = which == 0 ? q : which == 1 ? k : v;
        bf16_t* out = which == 0 ? qb : which == 1 ? kb : vb;
        size_t i = ((size_t)blk * 256 + tid) * 4;
        float4 vv = *(const float4*)(in + i);
        bf16x4 o;
        o[0] = (bf16_t)vv.x; o[1] = (bf16_t)vv.y; o[2] = (bf16_t)vv.z; o[3] = (bf16_t)vv.w;
        *(bf16x4*)(out + i) = o;
        return;
    }
    const float* W; bf16_t* WT; int K, N, k0, n0;
    if (id < 4096) {
        const int z = id >> 10, t3 = id & 1023;
        W = z == 0 ? wq : z == 1 ? wk : z == 2 ? wv : wo;
        WT = z == 0 ? wqT : z == 1 ? wkT : z == 2 ? wvT : woT;
        K = 1024; N = 1024; k0 = (t3 & 31) * 32; n0 = (t3 >> 5) * 32;
    } else if (id < 8192) {
        const int t3 = id - 4096;
        W = w1; WT = w1T; K = 1024; N = 4096;
        k0 = (t3 & 31) * 32; n0 = (t3 >> 5) * 32;
    } else {
        const int t3 = id - 8192;
        W = w2; WT = w2T; K = 4096; N = 1024;
        k0 = (t3 & 127) * 32; n0 = (t3 >> 7) * 32;
    }
    const int rr = tid >> 3, cc = (tid & 7) * 4;
    float4 vv = *(const float4*)(W + (size_t)(k0 + rr) * N + n0 + cc);
    t[rr][cc + 0] = vv.x; t[rr][cc + 1] = vv.y; t[rr][cc + 2] = vv.z; t[rr][cc + 3] = vv.w;
    __syncthreads();
    bf16x4 o;
    o[0] = (bf16_t)t[cc + 0][rr]; o[1] = (bf16_t)t[cc + 1][rr];
    o[2] = (bf16_t)t[cc + 2][rr]; o[3] = (bf16_t)t[cc + 3][rr];
    *(bf16x4*)(WT + (size_t)(n0 + rr) * K + k0 + cc) = o;
}

// ---------------------------------------------------------------------------
// 8-phase GEMM core v3 (R18): k-slice phases, mfma32, dedup'd LDS reads,
// ONE barrier per K-tile. Optional VTt: write output transposed into
// VT[B][H][64][S] (V-slice of QKV).
// ---------------------------------------------------------------------------
template<int NJT, bool RELU, bool OUT_BF16, bool OUT_F32>
__device__ __forceinline__ void gemm8p_core(const bf16_t* __restrict__ Ag, int lda,
                                            const bf16_t* __restrict__ Bg, int ldb,
                                            const float* __restrict__ bias, bool useBias,
                                            float* __restrict__ Cf,
                                            bf16_t* __restrict__ Cb,
                                            int N, int Klen, int m0, int n0,
                                            bf16_t* sA, bf16_t* sB,
                                            bf16_t* __restrict__ VTt) {
    constexpr int BELE = 8192 * NJT;
    constexpr int NBQ = 2 * NJT;
    const int tid = threadIdx.x;
    const int lane = tid & 63, w = tid >> 6;
    const int l31 = lane & 31, hi = lane >> 5;
    const int wm = (w >> 2) * 128;
    const int wn = (w & 3) * (32 * NJT);
    const int rs7 = l31 & 7;

    const int scol = ((tid & 7) ^ ((tid >> 3) & 7)) * 8;
    const bf16_t* aSrc = Ag + (size_t)(m0 + (tid >> 3)) * lda + scol;
    const bf16_t* bSrc = Bg + (size_t)(n0 + (tid >> 3)) * ldb + scol;

    f32x16 acc[4][NJT];
#pragma unroll
    for (int it = 0; it < 4; it++)
#pragma unroll
        for (int jt = 0; jt < NJT; jt++)
#pragma unroll
            for (int e = 0; e < 16; e++) acc[it][jt][e] = 0.f;

    auto stA = [&](int buf, int q, int k0) {
        gload_lds16(aSrc + (size_t)(q * 64) * lda + k0, sA + buf * 16384 + q * 4096 + tid * 8);
    };
    auto stB = [&](int buf, int q, int k0) {
        gload_lds16(bSrc + (size_t)(q * 64) * ldb + k0, sB + buf * BELE + q * 4096 + tid * 8);
    };

    bf16x8 a[4], b[NJT];
    auto RD = [&](int buf, int ks) {
        const bf16_t* bA = sA + buf * 16384;
        const bf16_t* bB = sB + buf * BELE;
        const int cs = ((((ks << 1) | hi)) ^ rs7) << 3;
#pragma unroll
        for (int it = 0; it < 4; it++)
            a[it] = *(const bf16x8*)(bA + (wm + it * 32 + l31) * 64 + cs);
#pragma unroll
        for (int jt = 0; jt < NJT; jt++)
            b[jt] = *(const bf16x8*)(bB + (wn + jt * 32 + l31) * 64 + cs);
    };
    auto MM = [&]() {
        __builtin_amdgcn_s_setprio(1);
#pragma unroll
        for (int it = 0; it < 4; it++)
#pragma unroll
            for (int jt = 0; jt < NJT; jt++)
                acc[it][jt] = mfma32(a[it], b[jt], acc[it][jt]);
        __builtin_amdgcn_s_setprio(0);
    };

#define LGKM0() do { asm volatile("s_waitcnt lgkmcnt(0)" ::: "memory"); \
                     __builtin_amdgcn_sched_barrier(0); } while (0)

    const int nk = Klen >> 6;
#pragma unroll
    for (int q = 0; q < 4; q++) stA(0, q, 0);
#pragma unroll
    for (int q = 0; q < NBQ; q++) stB(0, q, 0);
    asm volatile("s_waitcnt vmcnt(0)" ::: "memory");
    __builtin_amdgcn_s_barrier();

    for (int t = 0; t < nk; ++t) {
        const int buf = t & 1, nb = buf ^ 1;
        const int kn = (t + 1) << 6;
        const bool hn = (t + 1 < nk);
        RD(buf, 0);
        if (hn) { stA(nb, 0, kn); stA(nb, 1, kn); stA(nb, 2, kn); }
        LGKM0();
        MM();
        RD(buf, 1);
        if (hn) { stA(nb, 3, kn); stB(nb, 0, kn); if (NBQ > 1) stB(nb, 1, kn); }
        LGKM0();
        MM();
        RD(buf, 2);
        if (hn && NBQ > 2) { stB(nb, 2, kn); stB(nb, 3, kn); }
        LGKM0();
        MM();
        RD(buf, 3);
        LGKM0();
        MM();
        asm volatile("s_waitcnt vmcnt(0)" ::: "memory");
        __builtin_amdgcn_s_barrier();
    }
#undef LGKM0

    if (VTt) {
#pragma unroll
        for (int it = 0; it < 4; it++) {
#pragma unroll
            for (int jt = 0; jt < NJT; jt++) {
                const int n = n0 + wn + jt * 32 + l31;
                const float bv = bias[n];
                const int hh = n >> 6, dd = n & 63;
#pragma unroll
                for (int rq = 0; rq < 4; rq++) {
                    bf16x4 st;
#pragma unroll
                    for (int i2 = 0; i2 < 4; i2++)
                        st[i2] = (bf16_t)(acc[it][jt][rq * 4 + i2] + bv);
                    const int mrow = m0 + wm + it * 32 + rq * 8 + hi * 4;
                    const int bb = mrow >> 11, s = mrow & 2047;
                    *(bf16x4*)(VTt + (((size_t)(bb * 16 + hh)) * 64 + dd) * 2048 + s) = st;
                }
            }
        }
        return;
    }
#pragma unroll
    for (int it = 0; it < 4; it++) {
#pragma unroll
        for (int jt = 0; jt < NJT; jt++) {
            const int n = n0 + wn + jt * 32 + l31;
            const float bv = useBias ? bias[n] : 0.f;
#pragma unroll
            for (int e = 0; e < 16; e++) {
                const int mrow = m0 + wm + it * 32 + (e & 3) + ((e >> 2) << 3) + hi * 4;
                float val = acc[it][jt][e] + bv;
                if (RELU) val = fmaxf(val, 0.f);
                if (OUT_F32) Cf[(size_t)mrow * N + n] = val;
                if (OUT_BF16) Cb[(size_t)mrow * N + n] = (bf16_t)val;
            }
        }
    }
}

// split-K wrapper (z = K-chunk), BF16 partial outputs
template<int NJT, bool RELU>
__global__ __launch_bounds__(512, 1) void gemm8p(const bf16_t* __restrict__ A, int lda,
                                                 const bf16_t* __restrict__ Bt, int ldb,
                                                 const float* __restrict__ bias,
                                                 bf16_t* __restrict__ Cb0,
                                                 bf16_t* __restrict__ Cb1,
                                                 int N, int Klen) {
    __shared__ bf16_t sA[2 * 16384];
    __shared__ bf16_t sB[2 * 8192 * NJT];
    const int lin = blockIdx.x + gridDim.x * (blockIdx.y + gridDim.y * blockIdx.z);
    const int nwg = gridDim.x * gridDim.y * gridDim.z;
    const int sz = xcd_swz(lin, nwg);
    const int bx = sz % gridDim.x;
    const int rest = sz / gridDim.x;
    const int by = rest % gridDim.y;
    const int bz = rest / gridDim.y;
    const int koff = bz * Klen;
    gemm8p_core<NJT, RELU, true, false>(A + koff, lda, Bt + koff, ldb,
                                        bias, bz == 0,
                                        nullptr, bz ? Cb1 : Cb0, N, Klen,
                                        bx * 256, by * (128 * NJT), sA, sB, nullptr);
}

// non-split variant (FF1): bf16 out
template<int NJT, bool RELU>
__global__ __launch_bounds__(512, 1) void gemm8p_b(const bf16_t* __restrict__ A, int lda,
                                                   const bf16_t* __restrict__ Bt, int ldb,
                                                   const float* __restrict__ bias,
                                                   bf16_t* __restrict__ Cb,
                                                   int N, int Klen) {
    __shared__ bf16_t sA[2 * 16384];
    __shared__ bf16_t sB[2 * 8192 * NJT];
    const int lin = blockIdx.x + gridDim.x * (blockIdx.y + gridDim.y * blockIdx.z);
    const int nwg = gridDim.x * gridDim.y * gridDim.z;
    const int sz = xcd_swz(lin, nwg);
    const int bx = sz % gridDim.x;
    const int rest = sz / gridDim.x;
    const int by = rest % gridDim.y;
    gemm8p_core<NJT, RELU, true, false>(A, lda, Bt, ldb, bias, true,
                                        nullptr, Cb, N, Klen,
                                        bx * 256, by * (128 * NJT), sA, sB, nullptr);
}

// grouped QKV: z selects (A, W, bias); Q,K -> row-major; V -> VT transposed
__global__ __launch_bounds__(512, 1) void gemm_qkv8p(const bf16_t* __restrict__ A0,
                                                     const bf16_t* __restrict__ A1,
                                                     const bf16_t* __restrict__ A2,
                                                     const bf16_t* __restrict__ B0,
                                                     const bf16_t* __restrict__ B1,
                                                     const bf16_t* __restrict__ B2,
                                                     const float* __restrict__ b0,
                                                     const float* __restrict__ b1,
                                                     const float* __restrict__ b2,
                                                     bf16_t* __restrict__ C0,
                                                     bf16_t* __restrict__ C1,
                                                     bf16_t* __restrict__ VTout) {
    __shared__ bf16_t sA[2 * 16384];
    __shared__ bf16_t sB[2 * 16384];
    const int lin = blockIdx.x + gridDim.x * (blockIdx.y + gridDim.y * blockIdx.z);
    const int nwg = gridDim.x * gridDim.y * gridDim.z;
    const int sz = xcd_swz(lin, nwg);
    const int bx = sz % gridDim.x;
    const int rest = sz / gridDim.x;
    const int by = rest % gridDim.y;
    const int bz = rest / gridDim.y;
    const bf16_t* A = bz == 0 ? A0 : bz == 1 ? A1 : A2;
    const bf16_t* Bt = bz == 0 ? B0 : bz == 1 ? B1 : B2;
    const float* bias = bz == 0 ? b0 : bz == 1 ? b1 : b2;
    bf16_t* C = bz == 0 ? C0 : bz == 1 ? C1 : nullptr;
    bf16_t* VTt = bz == 2 ? VTout : nullptr;
    gemm8p_core<2, false, true, false>(A, 1024, Bt, 1024, bias, true,
                                       nullptr, C, 1024, 1024, bx * 256, by * 256,
                                       sA, sB, VTt);
}

// ---------------------------------------------------------------------------
// Flash attention v7: BARRIER-FREE 1-wave blocks. 1 wave = 32 q-rows over
// full S (64 tiles); stages its OWN K+V (16KB dbuf) -> all LDS data is
// produced and consumed by the same wave, so per-wave vmcnt(8) is the only
// sync (zero __syncthreads; in-order issue + lgkm-before-MFMA makes the
// buffer recycle safe). Split-KV merge eliminated (one wave owns the row).
// Grid (64,16,2)=2048 blocks, XCD-swizzled (2048%8==0).
// ---------------------------------------------------------------------------
__device__ __forceinline__ void flash_tile(
    const char* kt, const char* vt, int l31, int hi,
    const bf16x8 (&bq)[4],
    f32x16& o0, f32x16& o1, float& mC, float& l_run)
{
    bf16x8 ak[4];
#pragma unroll
    for (int kb = 0; kb < 4; kb++)
        ak[kb] = *(const bf16x8*)(kt + l31 * 128 + (((kb << 1) | hi) ^ (l31 & 7)) * 16);
    bf16x8 av[4];
#pragma unroll
    for (int db = 0; db < 2; db++)
#pragma unroll
        for (int kb = 0; kb < 2; kb++)
            av[db * 2 + kb] = *(const bf16x8*)(vt + (db * 32 + l31) * 64 + ((((kb << 1) | hi)) ^ ((l31 >> 1) & 3)) * 16);

    f32x16 s;
#pragma unroll
    for (int e = 0; e < 16; e++) s[e] = 0.f;
#pragma unroll
    for (int kb = 0; kb < 4; kb++) s = mfma32(ak[kb], bq[kb], s);

    float ma = fmaxf(fmaxf(s[0], s[1]), fmaxf(s[2], s[3]));
    float mb = fmaxf(fmaxf(s[4], s[5]), fmaxf(s[6], s[7]));
    float mc = fmaxf(fmaxf(s[8], s[9]), fmaxf(s[10], s[11]));
    float md = fmaxf(fmaxf(s[12], s[13]), fmaxf(s[14], s[15]));
    float pmaxC = fmaxf(fmaxf(ma, mb), fmaxf(mc, md)) * CF;

    if (!__all(pmaxC <= mC + THRC)) {
        int2v pr = plswap(__float_as_int(pmaxC), __float_as_int(pmaxC));
        float rowmaxC = fmaxf(__int_as_float(pr[0]), __int_as_float(pr[1]));
        float mnewC = fmaxf(mC, rowmaxC);
        float alpha = fexp2(mC - mnewC);
        mC = mnewC;
        l_run *= alpha;
#pragma unroll
        for (int e = 0; e < 16; e++) { o0[e] *= alpha; o1[e] *= alpha; }
    }

#pragma unroll
    for (int e = 0; e < 16; e++) s[e] = fexp2(__builtin_fmaf(s[e], CF, -mC));
    float t0 = (s[0] + s[1]) + (s[2] + s[3]);
    float t1 = (s[4] + s[5]) + (s[6] + s[7]);
    float t2 = (s[8] + s[9]) + (s[10] + s[11]);
    float t3 = (s[12] + s[13]) + (s[14] + s[15]);
    l_run += (t0 + t1) + (t2 + t3);

#pragma unroll
    for (int kb2 = 0; kb2 < 2; kb2++) {
        const int bse = kb2 * 8;
        int W0 = packbf(s[bse + 0], s[bse + 1]);
        int W1 = packbf(s[bse + 2], s[bse + 3]);
        int W2 = packbf(s[bse + 4], s[bse + 5]);
        int W3 = packbf(s[bse + 6], s[bse + 7]);
        int2v r02 = plswap(W0, W2);
        int2v r13 = plswap(W1, W3);
        int4v fw; fw[0] = r02[0]; fw[1] = r13[0]; fw[2] = r02[1]; fw[3] = r13[1];
        bf16x8 pf = __builtin_bit_cast(bf16x8, fw);
        o0 = mfma32(av[kb2], pf, o0);
        o1 = mfma32(av[2 + kb2], pf, o1);
    }
}

__global__ __launch_bounds__(64) void flash_attn(const bf16_t* __restrict__ Qp,
                                                 const bf16_t* __restrict__ Kp,
                                                 const bf16_t* __restrict__ VT,
                                                 bf16_t* __restrict__ Oa) {
    __shared__ alignas(16) char lds[2][8192];   // [buf][K 4KB | V 4KB]
    const int lane = threadIdx.x;               // 0..63
    const int l31 = lane & 31, hi = lane >> 5;

    // XCD swizzle: 2048 blocks = 8 XCDs x 256
    const int lin = blockIdx.x + (blockIdx.y << 6) + (blockIdx.z << 10);
    const int swz = (lin & 7) * 256 + (lin >> 3);
    const int qb = swz & 63;
    const int h = (swz >> 6) & 15;
    const int b = swz >> 10;

    const int q0 = qb * 32;

    const bf16_t* Qb = Qp + (size_t)b * S_SZ * D_MODEL + h * HEAD_DIM;
    const bf16_t* Kb = Kp + (size_t)b * S_SZ * D_MODEL + h * HEAD_DIM;
    const bf16_t* Vb = VT + ((size_t)(b * NUM_HEADS + h) * HEAD_DIM) * S_SZ;

    // pre-swizzled per-lane staging sources (same verified mappings as v5)
    const bf16_t* srcK = Kb + (size_t)(lane >> 3) * D_MODEL + ((lane & 7) ^ (lane >> 3)) * 8;
    const bf16_t* srcV = Vb + (size_t)(lane >> 2) * S_SZ + ((lane & 3) ^ ((lane >> 3) & 3)) * 8;

    char* dK0 = &lds[0][0] + lane * 16;
    char* dK1 = &lds[1][0] + lane * 16;
    char* dV0 = &lds[0][4096] + lane * 16;
    char* dV1 = &lds[1][4096] + lane * 16;

#define STG(BUF, T) do { \
    const bf16_t* sk_ = srcK + (size_t)((T) * 32) * D_MODEL; \
    const bf16_t* sv_ = srcV + (T) * 32; \
    char* dk_ = (BUF) ? dK1 : dK0; \
    char* dv_ = (BUF) ? dV1 : dV0; \
    _Pragma("unroll") \
    for (int ii = 0; ii < 4; ii++) \
        gload_lds16(sk_ + (size_t)(ii * 8) * D_MODEL, dk_ + ii * 1024); \
    _Pragma("unroll") \
    for (int ii = 0; ii < 4; ii++) \
        gload_lds16(sv_ + (size_t)(ii * 16) * S_SZ, dv_ + ii * 1024); \
} while (0)

    bf16x8 bq[4];
#pragma unroll
    for (int kb = 0; kb < 4; kb++)
        bq[kb] = *(const bf16x8*)(Qb + (size_t)(q0 + l31) * D_MODEL + kb * 16 + hi * 8);

    f32x16 o0, o1;
#pragma unroll
    for (int e = 0; e < 16; e++) { o0[e] = 0.f; o1[e] = 0.f; }
    float mC = -1e30f, l_run = 0.f;

    STG(0, 0);
    for (int t = 0; t < 64; ++t) {
        const int buf = t & 1;
        if (t + 1 < 64) {
            STG(buf ^ 1, t + 1);
            asm volatile("s_waitcnt vmcnt(8)" ::: "memory");   // tile t landed
        } else {
            asm volatile("s_waitcnt vmcnt(0)" ::: "memory");
        }
        __builtin_amdgcn_sched_barrier(0);
        flash_tile(buf ? &lds[1][0] : &lds[0][0],
                   buf ? &lds[1][4096] : &lds[0][4096],
                   l31, hi, bq, o0, o1, mC, l_run);
    }
#undef STG

    // epilogue: cross-hi l combine (in-wave), direct normalized write
    int2v lp = plswap(__float_as_int(l_run), __float_as_int(l_run));
    l_run = __int_as_float(lp[0]) + __int_as_float(lp[1]);
    const float linv = 1.f / l_run;
    bf16_t* Orow = Oa + ((size_t)b * S_SZ + q0 + l31) * D_MODEL + h * HEAD_DIM;
#pragma unroll
    for (int db = 0; db < 2; db++) {
#pragma unroll
        for (int rq = 0; rq < 4; rq++) {
            bf16x4 st;
#pragma unroll
            for (int i = 0; i < 4; i++) {
                const int e = rq * 4 + i;
                st[i] = (bf16_t)((db ? o1[e] : o0[e]) * linv);
            }
            *(bf16x4*)(Orow + db * 32 + rq * 8 + hi * 4) = st;
        }
    }
}

// ---------------------------------------------------------------------------
// LayerNorm over 1024: A,A2 bf16 split-K partials; R bf16 residual.
// Outputs: optional f32 Xf, optional bf16 Xb.
// ---------------------------------------------------------------------------
__global__ __launch_bounds__(256) void ln_fused(const bf16_t* __restrict__ A,
                                                const bf16_t* __restrict__ A2,
                                                const bf16_t* __restrict__ R,
                                                const float* __restrict__ gamma,
                                                const float* __restrict__ beta,
                                                float* __restrict__ Xf,
                                                bf16_t* __restrict__ Xb) {
    __shared__ float red[8];
    int row = blockIdx.x, tid = threadIdx.x;
    size_t base = (size_t)row * D_MODEL + tid * 4;
    bf16x4 a = *(const bf16x4*)(A + base);
    bf16x4 a2 = *(const bf16x4*)(A2 + base);
    bf16x4 rv = *(const bf16x4*)(R + base);
    float v0 = (float)a[0] + (float)a2[0] + (float)rv[0];
    float v1 = (float)a[1] + (float)a2[1] + (float)rv[1];
    float v2 = (float)a[2] + (float)a2[2] + (float)rv[2];
    float v3 = (float)a[3] + (float)a2[3] + (float)rv[3];
    float s = v0 + v1 + v2 + v3;
    float q = v0 * v0 + v1 * v1 + v2 * v2 + v3 * v3;
#pragma unroll
    for (int off = 32; off; off >>= 1) { s += __shfl_down(s, off); q += __shfl_down(q, off); }
    if ((tid & 63) == 0) { red[tid >> 6] = s; red[4 + (tid >> 6)] = q; }
    __syncthreads();
    s = red[0] + red[1] + red[2] + red[3];
    q = red[4] + red[5] + red[6] + red[7];
    float mean = s * (1.f / D_MODEL);
    float var = q * (1.f / D_MODEL) - mean * mean;
    float rstd = rsqrtf(var + 1e-5f);
    float4 gm = *(const float4*)(gamma + tid * 4);
    float4 bt = *(const float4*)(beta + tid * 4);
    float y0 = (v0 - mean) * rstd * gm.x + bt.x;
    float y1 = (v1 - mean) * rstd * gm.y + bt.y;
    float y2 = (v2 - mean) * rstd * gm.z + bt.z;
    float y3 = (v3 - mean) * rstd * gm.w + bt.w;
    if (Xf) {
        float4 yo; yo.x = y0; yo.y = y1; yo.z = y2; yo.w = y3;
        *(float4*)(Xf + base) = yo;
    }
    if (Xb) {
        bf16x4 ob; ob[0] = (bf16_t)y0; ob[1] = (bf16_t)y1; ob[2] = (bf16_t)y2; ob[3] = (bf16_t)y3;
        *(bf16x4*)(Xb + base) = ob;
    }
}

// ---------------------------------------------------------------------------
extern "C" void kernel_launch(void* const* d_in, const int* in_sizes, int n_in,
                              void* d_out, int out_size, void* d_ws, size_t ws_size,
                              hipStream_t stream) {
    const float* value = (const float*)d_in[0];
    const float* key   = (const float*)d_in[1];
    const float* query = (const float*)d_in[2];
    const float* wq = (const float*)d_in[3];
    const float* bq = (const float*)d_in[4];
    const float* wk = (const float*)d_in[5];
    const float* bk = (const float*)d_in[6];
    const float* wv = (const float*)d_in[7];
    const float* bv = (const float*)d_in[8];
    const float* wo = (const float*)d_in[9];
    const float* bo = (const float*)d_in[10];
    const float* g1 = (const float*)d_in[11];
    const float* beta1 = (const float*)d_in[12];
    const float* w1 = (const float*)d_in[13];
    const float* b1 = (const float*)d_in[14];
    const float* w2 = (const float*)d_in[15];
    const float* b2 = (const float*)d_in[16];
    const float* g2 = (const float*)d_in[17];
    const float* beta2 = (const float*)d_in[18];
    (void)in_sizes; (void)n_in; (void)out_size; (void)ws_size;

    const size_t MB = 1ull << 20;
    char* ws = (char*)d_ws;
    bf16_t* wqT = (bf16_t*)(ws + 0 * MB);
    bf16_t* wkT = (bf16_t*)(ws + 2 * MB);
    bf16_t* wvT = (bf16_t*)(ws + 4 * MB);
    bf16_t* woT = (bf16_t*)(ws + 6 * MB);
    bf16_t* w1T = (bf16_t*)(ws + 8 * MB);
    bf16_t* w2T = (bf16_t*)(ws + 16 * MB);
    bf16_t* q_bf = (bf16_t*)(ws + 24 * MB);  // LIVE until LN1 (residual)
    bf16_t* k_bf = (bf16_t*)(ws + 32 * MB);
    bf16_t* v_bf = (bf16_t*)(ws + 40 * MB);
    bf16_t* Qp  = (bf16_t*)(ws + 48 * MB);
    bf16_t* Kp  = (bf16_t*)(ws + 56 * MB);
    bf16_t* VT  = (bf16_t*)(ws + 64 * MB);   // [B][H][64][S], written by QKV
    bf16_t* attn = (bf16_t*)(ws + 88 * MB);  // q_bf stays live
    bf16_t* woP0 = (bf16_t*)(ws + 32 * MB);  // reuse k_bf (dead after QKV)
    bf16_t* woP1 = (bf16_t*)(ws + 42 * MB);
    bf16_t* x_b = (bf16_t*)(ws + 96 * MB);   // LN1 out, LIVE until LN2
    bf16_t* h_b = (bf16_t*)(ws + 32 * MB);   // reuse woP (dead after LN1), 32MB
    bf16_t* ffP0 = (bf16_t*)(ws + 64 * MB);  // reuse VT (dead after flash)
    bf16_t* ffP1 = (bf16_t*)(ws + 72 * MB);

    dim3 blk(256);
    dim3 blk512(512);

    // 1) single prep launch: input casts + all weight transposes
    prep_all<<<24576, blk, 0, stream>>>(query, key, value, q_bf, k_bf, v_bf,
                                        wq, wk, wv, wo, w1, w2,
                                        wqT, wkT, wvT, woT, w1T, w2T);

    // 2) grouped QKV projection; V written directly into VT layout
    gemm_qkv8p<<<dim3(16, 4, 3), blk512, 0, stream>>>(q_bf, k_bf, v_bf, wqT, wkT, wvT,
                                                      bq, bk, bv, Qp, Kp, VT);

    // 3) flash attention v7 (barrier-free 1-wave blocks)
    flash_attn<<<dim3(64, 16, 2), dim3(64), 0, stream>>>(Qp, Kp, VT, attn);

    // 4) WO projection (split-K=2, bf16 partials)
    gemm8p<1, false><<<dim3(16, 8, 2), blk512, 0, stream>>>(attn, 1024, woT, 1024, bo, woP0, woP1, D_MODEL, 512);

    // 5) LN1: x = LN(woP0 + woP1 + q_bf)
    ln_fused<<<4096, blk, 0, stream>>>(woP0, woP1, q_bf, g1, beta1, nullptr, x_b);

    // 6) FF1 + ReLU (BN=256, bf16 out)
    gemm8p_b<2, true><<<dim3(16, 16, 1), blk512, 0, stream>>>(x_b, 1024, w1T, 1024, b1, h_b, FF_DIM, 1024);

    // 7) FF2 (split-K=2, bf16 partials)
    gemm8p<1, false><<<dim3(16, 8, 2), blk512, 0, stream>>>(h_b, 4096, w2T, 4096, b2, ffP0, ffP1, D_MODEL, 2048);

    // 8) LN2 -> d_out
    ln_fused<<<4096, blk, 0, stream>>>(ffP0, ffP1, x_b, g2, beta2, (float*)d_out, nullptr);
}

// Round 26
// 221.578 us; speedup vs baseline: 1.1216x; 1.1216x over previous
//
#include <hip/hip_runtime.h>
#include <hip/hip_bf16.h>
#include <cstdint>
#include <math.h>

typedef __bf16 bf16_t;
typedef __attribute__((ext_vector_type(2))) __bf16 bf16x2;
typedef __attribute__((ext_vector_type(4))) __bf16 bf16x4;
typedef __attribute__((ext_vector_type(8))) __bf16 bf16x8;
typedef __attribute__((ext_vector_type(4))) float f32x4;
typedef __attribute__((ext_vector_type(16))) float f32x16;
typedef __attribute__((ext_vector_type(2))) int int2v;
typedef __attribute__((ext_vector_type(4))) int int4v;

#define B_SZ 2
#define S_SZ 2048
#define D_MODEL 1024
#define NUM_HEADS 16
#define HEAD_DIM 64
#define FF_DIM 4096
#define M_ROWS (B_SZ * S_SZ)   // 4096

// exp2-domain scale: 0.125 (1/sqrt(64)) * log2(e)
#define CF 0.180336880f
#define THRC 2.0f

__device__ __forceinline__ float fexp2(float x) { return __builtin_amdgcn_exp2f(x); }

// ---------------------------------------------------------------------------
__device__ __forceinline__ void gload_lds16(const void* g, void* lds) {
    __builtin_amdgcn_global_load_lds(
        (const __attribute__((address_space(1))) void*)(uintptr_t)g,
        (__attribute__((address_space(3))) void*)(uint32_t)(uintptr_t)lds,
        16, 0, 0);
}

__device__ __forceinline__ f32x4 mfma16(bf16x8 a, bf16x8 b, f32x4 c) {
    return __builtin_amdgcn_mfma_f32_16x16x32_bf16(a, b, c, 0, 0, 0);
}
__device__ __forceinline__ f32x16 mfma32(bf16x8 a, bf16x8 b, f32x16 c) {
    return __builtin_amdgcn_mfma_f32_32x32x16_bf16(a, b, c, 0, 0, 0);
}
__device__ __forceinline__ int2v plswap(int a, int b) {
    return __builtin_amdgcn_permlane32_swap(a, b, false, false);
}
__device__ __forceinline__ int packbf(float a, float b) {
    bf16x2 t; t[0] = (bf16_t)a; t[1] = (bf16_t)b;
    return __builtin_bit_cast(int, t);
}

__device__ __forceinline__ int xcd_swz(int lin, int nwg) {
    return (lin & 7) * (nwg >> 3) + (lin >> 3);
}

// ---------------------------------------------------------------------------
// ONE prep launch: blocks [0,4096) square-W transposes, [4096,8192) w1,
// [8192,12288) w2, [12288,24576) the three f32->bf16 input casts.
// ---------------------------------------------------------------------------
__global__ __launch_bounds__(256) void prep_all(
    const float* __restrict__ q, const float* __restrict__ k, const float* __restrict__ v,
    bf16_t* __restrict__ qb, bf16_t* __restrict__ kb, bf16_t* __restrict__ vb,
    const float* __restrict__ wq, const float* __restrict__ wk,
    const float* __restrict__ wv, const float* __restrict__ wo,
    const float* __restrict__ w1, const float* __restrict__ w2,
    bf16_t* __restrict__ wqT, bf16_t* __restrict__ wkT,
    bf16_t* __restrict__ wvT, bf16_t* __restrict__ woT,
    bf16_t* __restrict__ w1T, bf16_t* __restrict__ w2T) {
    __shared__ float t[32][33];
    const int id = blockIdx.x;
    const int tid = threadIdx.x;
    if (id >= 12288) {
        const int t2 = id - 12288;
        const int which = t2 >> 12, blk = t2 & 4095;
        const float* in = which == 0 ? q : which == 1 ? k : v;
        bf16_t* out = which == 0 ? qb : which == 1 ? kb : vb;
        size_t i = ((size_t)blk * 256 + tid) * 4;
        float4 vv = *(const float4*)(in + i);
        bf16x4 o;
        o[0] = (bf16_t)vv.x; o[1] = (bf16_t)vv.y; o[2] = (bf16_t)vv.z; o[3] = (bf16_t)vv.w;
        *(bf16x4*)(out + i) = o;
        return;
    }
    const float* W; bf16_t* WT; int K, N, k0, n0;
    if (id < 4096) {
        const int z = id >> 10, t3 = id & 1023;
        W = z == 0 ? wq : z == 1 ? wk : z == 2 ? wv : wo;
        WT = z == 0 ? wqT : z == 1 ? wkT : z == 2 ? wvT : woT;
        K = 1024; N = 1024; k0 = (t3 & 31) * 32; n0 = (t3 >> 5) * 32;
    } else if (id < 8192) {
        const int t3 = id - 4096;
        W = w1; WT = w1T; K = 1024; N = 4096;
        k0 = (t3 & 31) * 32; n0 = (t3 >> 5) * 32;
    } else {
        const int t3 = id - 8192;
        W = w2; WT = w2T; K = 4096; N = 1024;
        k0 = (t3 & 127) * 32; n0 = (t3 >> 7) * 32;
    }
    const int rr = tid >> 3, cc = (tid & 7) * 4;
    float4 vv = *(const float4*)(W + (size_t)(k0 + rr) * N + n0 + cc);
    t[rr][cc + 0] = vv.x; t[rr][cc + 1] = vv.y; t[rr][cc + 2] = vv.z; t[rr][cc + 3] = vv.w;
    __syncthreads();
    bf16x4 o;
    o[0] = (bf16_t)t[cc + 0][rr]; o[1] = (bf16_t)t[cc + 1][rr];
    o[2] = (bf16_t)t[cc + 2][rr]; o[3] = (bf16_t)t[cc + 3][rr];
    *(bf16x4*)(WT + (size_t)(n0 + rr) * K + k0 + cc) = o;
}

// ---------------------------------------------------------------------------
// 8-phase GEMM core v3 (R18): k-slice phases, mfma32, dedup'd LDS reads,
// ONE barrier per K-tile. Optional VTt: write output transposed into
// VT[B][H][64][S] (V-slice of QKV).
// ---------------------------------------------------------------------------
template<int NJT, bool RELU, bool OUT_BF16, bool OUT_F32>
__device__ __forceinline__ void gemm8p_core(const bf16_t* __restrict__ Ag, int lda,
                                            const bf16_t* __restrict__ Bg, int ldb,
                                            const float* __restrict__ bias, bool useBias,
                                            float* __restrict__ Cf,
                                            bf16_t* __restrict__ Cb,
                                            int N, int Klen, int m0, int n0,
                                            bf16_t* sA, bf16_t* sB,
                                            bf16_t* __restrict__ VTt) {
    constexpr int BELE = 8192 * NJT;
    constexpr int NBQ = 2 * NJT;
    const int tid = threadIdx.x;
    const int lane = tid & 63, w = tid >> 6;
    const int l31 = lane & 31, hi = lane >> 5;
    const int wm = (w >> 2) * 128;
    const int wn = (w & 3) * (32 * NJT);
    const int rs7 = l31 & 7;

    const int scol = ((tid & 7) ^ ((tid >> 3) & 7)) * 8;
    const bf16_t* aSrc = Ag + (size_t)(m0 + (tid >> 3)) * lda + scol;
    const bf16_t* bSrc = Bg + (size_t)(n0 + (tid >> 3)) * ldb + scol;

    f32x16 acc[4][NJT];
#pragma unroll
    for (int it = 0; it < 4; it++)
#pragma unroll
        for (int jt = 0; jt < NJT; jt++)
#pragma unroll
            for (int e = 0; e < 16; e++) acc[it][jt][e] = 0.f;

    auto stA = [&](int buf, int q, int k0) {
        gload_lds16(aSrc + (size_t)(q * 64) * lda + k0, sA + buf * 16384 + q * 4096 + tid * 8);
    };
    auto stB = [&](int buf, int q, int k0) {
        gload_lds16(bSrc + (size_t)(q * 64) * ldb + k0, sB + buf * BELE + q * 4096 + tid * 8);
    };

    bf16x8 a[4], b[NJT];
    auto RD = [&](int buf, int ks) {
        const bf16_t* bA = sA + buf * 16384;
        const bf16_t* bB = sB + buf * BELE;
        const int cs = ((((ks << 1) | hi)) ^ rs7) << 3;
#pragma unroll
        for (int it = 0; it < 4; it++)
            a[it] = *(const bf16x8*)(bA + (wm + it * 32 + l31) * 64 + cs);
#pragma unroll
        for (int jt = 0; jt < NJT; jt++)
            b[jt] = *(const bf16x8*)(bB + (wn + jt * 32 + l31) * 64 + cs);
    };
    auto MM = [&]() {
        __builtin_amdgcn_s_setprio(1);
#pragma unroll
        for (int it = 0; it < 4; it++)
#pragma unroll
            for (int jt = 0; jt < NJT; jt++)
                acc[it][jt] = mfma32(a[it], b[jt], acc[it][jt]);
        __builtin_amdgcn_s_setprio(0);
    };

#define LGKM0() do { asm volatile("s_waitcnt lgkmcnt(0)" ::: "memory"); \
                     __builtin_amdgcn_sched_barrier(0); } while (0)

    const int nk = Klen >> 6;
#pragma unroll
    for (int q = 0; q < 4; q++) stA(0, q, 0);
#pragma unroll
    for (int q = 0; q < NBQ; q++) stB(0, q, 0);
    asm volatile("s_waitcnt vmcnt(0)" ::: "memory");
    __builtin_amdgcn_s_barrier();

    for (int t = 0; t < nk; ++t) {
        const int buf = t & 1, nb = buf ^ 1;
        const int kn = (t + 1) << 6;
        const bool hn = (t + 1 < nk);
        RD(buf, 0);
        if (hn) { stA(nb, 0, kn); stA(nb, 1, kn); stA(nb, 2, kn); }
        LGKM0();
        MM();
        RD(buf, 1);
        if (hn) { stA(nb, 3, kn); stB(nb, 0, kn); if (NBQ > 1) stB(nb, 1, kn); }
        LGKM0();
        MM();
        RD(buf, 2);
        if (hn && NBQ > 2) { stB(nb, 2, kn); stB(nb, 3, kn); }
        LGKM0();
        MM();
        RD(buf, 3);
        LGKM0();
        MM();
        asm volatile("s_waitcnt vmcnt(0)" ::: "memory");
        __builtin_amdgcn_s_barrier();
    }
#undef LGKM0

    if (VTt) {
#pragma unroll
        for (int it = 0; it < 4; it++) {
#pragma unroll
            for (int jt = 0; jt < NJT; jt++) {
                const int n = n0 + wn + jt * 32 + l31;
                const float bv = bias[n];
                const int hh = n >> 6, dd = n & 63;
#pragma unroll
                for (int rq = 0; rq < 4; rq++) {
                    bf16x4 st;
#pragma unroll
                    for (int i2 = 0; i2 < 4; i2++)
                        st[i2] = (bf16_t)(acc[it][jt][rq * 4 + i2] + bv);
                    const int mrow = m0 + wm + it * 32 + rq * 8 + hi * 4;
                    const int bb = mrow >> 11, s = mrow & 2047;
                    *(bf16x4*)(VTt + (((size_t)(bb * 16 + hh)) * 64 + dd) * 2048 + s) = st;
                }
            }
        }
        return;
    }
#pragma unroll
    for (int it = 0; it < 4; it++) {
#pragma unroll
        for (int jt = 0; jt < NJT; jt++) {
            const int n = n0 + wn + jt * 32 + l31;
            const float bv = useBias ? bias[n] : 0.f;
#pragma unroll
            for (int e = 0; e < 16; e++) {
                const int mrow = m0 + wm + it * 32 + (e & 3) + ((e >> 2) << 3) + hi * 4;
                float val = acc[it][jt][e] + bv;
                if (RELU) val = fmaxf(val, 0.f);
                if (OUT_F32) Cf[(size_t)mrow * N + n] = val;
                if (OUT_BF16) Cb[(size_t)mrow * N + n] = (bf16_t)val;
            }
        }
    }
}

// split-K wrapper (z = K-chunk), BF16 partial outputs
template<int NJT, bool RELU>
__global__ __launch_bounds__(512, 1) void gemm8p(const bf16_t* __restrict__ A, int lda,
                                                 const bf16_t* __restrict__ Bt, int ldb,
                                                 const float* __restrict__ bias,
                                                 bf16_t* __restrict__ Cb0,
                                                 bf16_t* __restrict__ Cb1,
                                                 int N, int Klen) {
    __shared__ bf16_t sA[2 * 16384];
    __shared__ bf16_t sB[2 * 8192 * NJT];
    const int lin = blockIdx.x + gridDim.x * (blockIdx.y + gridDim.y * blockIdx.z);
    const int nwg = gridDim.x * gridDim.y * gridDim.z;
    const int sz = xcd_swz(lin, nwg);
    const int bx = sz % gridDim.x;
    const int rest = sz / gridDim.x;
    const int by = rest % gridDim.y;
    const int bz = rest / gridDim.y;
    const int koff = bz * Klen;
    gemm8p_core<NJT, RELU, true, false>(A + koff, lda, Bt + koff, ldb,
                                        bias, bz == 0,
                                        nullptr, bz ? Cb1 : Cb0, N, Klen,
                                        bx * 256, by * (128 * NJT), sA, sB, nullptr);
}

// non-split variant (FF1): bf16 out
template<int NJT, bool RELU>
__global__ __launch_bounds__(512, 1) void gemm8p_b(const bf16_t* __restrict__ A, int lda,
                                                   const bf16_t* __restrict__ Bt, int ldb,
                                                   const float* __restrict__ bias,
                                                   bf16_t* __restrict__ Cb,
                                                   int N, int Klen) {
    __shared__ bf16_t sA[2 * 16384];
    __shared__ bf16_t sB[2 * 8192 * NJT];
    const int lin = blockIdx.x + gridDim.x * (blockIdx.y + gridDim.y * blockIdx.z);
    const int nwg = gridDim.x * gridDim.y * gridDim.z;
    const int sz = xcd_swz(lin, nwg);
    const int bx = sz % gridDim.x;
    const int rest = sz / gridDim.x;
    const int by = rest % gridDim.y;
    gemm8p_core<NJT, RELU, true, false>(A, lda, Bt, ldb, bias, true,
                                        nullptr, Cb, N, Klen,
                                        bx * 256, by * (128 * NJT), sA, sB, nullptr);
}

// grouped QKV: z selects (A, W, bias); Q,K -> row-major; V -> VT transposed
__global__ __launch_bounds__(512, 1) void gemm_qkv8p(const bf16_t* __restrict__ A0,
                                                     const bf16_t* __restrict__ A1,
                                                     const bf16_t* __restrict__ A2,
                                                     const bf16_t* __restrict__ B0,
                                                     const bf16_t* __restrict__ B1,
                                                     const bf16_t* __restrict__ B2,
                                                     const float* __restrict__ b0,
                                                     const float* __restrict__ b1,
                                                     const float* __restrict__ b2,
                                                     bf16_t* __restrict__ C0,
                                                     bf16_t* __restrict__ C1,
                                                     bf16_t* __restrict__ VTout) {
    __shared__ bf16_t sA[2 * 16384];
    __shared__ bf16_t sB[2 * 16384];
    const int lin = blockIdx.x + gridDim.x * (blockIdx.y + gridDim.y * blockIdx.z);
    const int nwg = gridDim.x * gridDim.y * gridDim.z;
    const int sz = xcd_swz(lin, nwg);
    const int bx = sz % gridDim.x;
    const int rest = sz / gridDim.x;
    const int by = rest % gridDim.y;
    const int bz = rest / gridDim.y;
    const bf16_t* A = bz == 0 ? A0 : bz == 1 ? A1 : A2;
    const bf16_t* Bt = bz == 0 ? B0 : bz == 1 ? B1 : B2;
    const float* bias = bz == 0 ? b0 : bz == 1 ? b1 : b2;
    bf16_t* C = bz == 0 ? C0 : bz == 1 ? C1 : nullptr;
    bf16_t* VTt = bz == 2 ? VTout : nullptr;
    gemm8p_core<2, false, true, false>(A, 1024, Bt, 1024, bias, true,
                                       nullptr, C, 1024, 1024, bx * 256, by * 256,
                                       sA, sB, VTt);
}

// ---------------------------------------------------------------------------
// Flash attention v5 (defer-max, 2-buffer ring - known-good 62.5us config)
// ---------------------------------------------------------------------------
__device__ __forceinline__ void flash_tile(
    const char* kt, const char* vt, int l31, int hi,
    const bf16x8 (&bq)[4],
    f32x16& o0, f32x16& o1, float& mC, float& l_run)
{
    bf16x8 ak[4];
#pragma unroll
    for (int kb = 0; kb < 4; kb++)
        ak[kb] = *(const bf16x8*)(kt + l31 * 128 + (((kb << 1) | hi) ^ (l31 & 7)) * 16);
    bf16x8 av[4];
#pragma unroll
    for (int db = 0; db < 2; db++)
#pragma unroll
        for (int kb = 0; kb < 2; kb++)
            av[db * 2 + kb] = *(const bf16x8*)(vt + (db * 32 + l31) * 64 + ((((kb << 1) | hi)) ^ ((l31 >> 1) & 3)) * 16);

    f32x16 s;
#pragma unroll
    for (int e = 0; e < 16; e++) s[e] = 0.f;
#pragma unroll
    for (int kb = 0; kb < 4; kb++) s = mfma32(ak[kb], bq[kb], s);

    float ma = fmaxf(fmaxf(s[0], s[1]), fmaxf(s[2], s[3]));
    float mb = fmaxf(fmaxf(s[4], s[5]), fmaxf(s[6], s[7]));
    float mc = fmaxf(fmaxf(s[8], s[9]), fmaxf(s[10], s[11]));
    float md = fmaxf(fmaxf(s[12], s[13]), fmaxf(s[14], s[15]));
    float pmaxC = fmaxf(fmaxf(ma, mb), fmaxf(mc, md)) * CF;

    if (!__all(pmaxC <= mC + THRC)) {
        int2v pr = plswap(__float_as_int(pmaxC), __float_as_int(pmaxC));
        float rowmaxC = fmaxf(__int_as_float(pr[0]), __int_as_float(pr[1]));
        float mnewC = fmaxf(mC, rowmaxC);
        float alpha = fexp2(mC - mnewC);
        mC = mnewC;
        l_run *= alpha;
#pragma unroll
        for (int e = 0; e < 16; e++) { o0[e] *= alpha; o1[e] *= alpha; }
    }

#pragma unroll
    for (int e = 0; e < 16; e++) s[e] = fexp2(__builtin_fmaf(s[e], CF, -mC));
    float t0 = (s[0] + s[1]) + (s[2] + s[3]);
    float t1 = (s[4] + s[5]) + (s[6] + s[7]);
    float t2 = (s[8] + s[9]) + (s[10] + s[11]);
    float t3 = (s[12] + s[13]) + (s[14] + s[15]);
    l_run += (t0 + t1) + (t2 + t3);

#pragma unroll
    for (int kb2 = 0; kb2 < 2; kb2++) {
        const int bse = kb2 * 8;
        int W0 = packbf(s[bse + 0], s[bse + 1]);
        int W1 = packbf(s[bse + 2], s[bse + 3]);
        int W2 = packbf(s[bse + 4], s[bse + 5]);
        int W3 = packbf(s[bse + 6], s[bse + 7]);
        int2v r02 = plswap(W0, W2);
        int2v r13 = plswap(W1, W3);
        int4v fw; fw[0] = r02[0]; fw[1] = r13[0]; fw[2] = r02[1]; fw[3] = r13[1];
        bf16x8 pf = __builtin_bit_cast(bf16x8, fw);
        o0 = mfma32(av[kb2], pf, o0);
        o1 = mfma32(av[2 + kb2], pf, o1);
    }
}

__global__ __launch_bounds__(256) void flash_attn(const bf16_t* __restrict__ Qp,
                                                  const bf16_t* __restrict__ Kp,
                                                  const bf16_t* __restrict__ VT,
                                                  bf16_t* __restrict__ Oa) {
    __shared__ alignas(16) char lds[2][2][8192];
    const int tid = threadIdx.x;
    const int lane = tid & 63;
    const int wave = tid >> 6;
    const int half = wave >> 1;
    const int qt = wave & 1;
    const int l31 = lane & 31, hi = lane >> 5;

    const int lin = blockIdx.x + (blockIdx.y << 5) + (blockIdx.z << 9);
    const int swz = (lin & 7) * 128 + (lin >> 3);
    const int qb = swz & 31;
    const int h = (swz >> 5) & 15;
    const int b = swz >> 9;

    const int q0 = qb * 64 + qt * 32;

    const bf16_t* Qb = Qp + (size_t)b * S_SZ * D_MODEL + h * HEAD_DIM;
    const bf16_t* Kb = Kp + (size_t)b * S_SZ * D_MODEL + h * HEAD_DIM;
    const bf16_t* Vb = VT + ((size_t)(b * NUM_HEADS + h) * HEAD_DIM) * S_SZ;

    const int sh = wave & 1;
    const int skvbase = sh * (S_SZ / 2);
    const bool kRole = wave < 2;

    const bf16_t* src_run;
    size_t inner_stride;
    size_t tile_stride;
    char* dst0;
    char* dst1;
    if (kRole) {
        src_run = Kb + (size_t)(skvbase + (lane >> 3)) * D_MODEL + ((lane & 7) ^ (lane >> 3)) * 8;
        inner_stride = (size_t)8 * D_MODEL;
        tile_stride = (size_t)32 * D_MODEL;
        dst0 = &lds[0][sh][0] + lane * 16;
        dst1 = &lds[1][sh][0] + lane * 16;
    } else {
        src_run = Vb + (size_t)(lane >> 2) * S_SZ + skvbase + ((lane & 3) ^ ((lane >> 3) & 3)) * 8;
        inner_stride = (size_t)16 * S_SZ;
        tile_stride = 32;
        dst0 = &lds[0][sh][4096] + lane * 16;
        dst1 = &lds[1][sh][4096] + lane * 16;
    }

    bf16x8 bq[4];
#pragma unroll
    for (int kb = 0; kb < 4; kb++)
        bq[kb] = *(const bf16x8*)(Qb + (size_t)(q0 + l31) * D_MODEL + kb * 16 + hi * 8);

    f32x16 o0, o1;
#pragma unroll
    for (int e = 0; e < 16; e++) { o0[e] = 0.f; o1[e] = 0.f; }
    float mC = -1e30f, l_run = 0.f;

    const char* kt0 = &lds[0][half][0];
    const char* vt0 = &lds[0][half][4096];
    const char* kt1 = &lds[1][half][0];
    const char* vt1 = &lds[1][half][4096];

#pragma unroll
    for (int ii = 0; ii < 4; ii++)
        gload_lds16(src_run + ii * inner_stride, dst0 + ii * 1024);
    src_run += tile_stride;
    __syncthreads();

    for (int t = 0; t < 32; t += 2) {
#pragma unroll
        for (int ii = 0; ii < 4; ii++)
            gload_lds16(src_run + ii * inner_stride, dst1 + ii * 1024);
        src_run += tile_stride;
        flash_tile(kt0, vt0, l31, hi, bq, o0, o1, mC, l_run);
        __syncthreads();

        if (t + 2 < 32) {
#pragma unroll
            for (int ii = 0; ii < 4; ii++)
                gload_lds16(src_run + ii * inner_stride, dst0 + ii * 1024);
            src_run += tile_stride;
        }
        flash_tile(kt1, vt1, l31, hi, bq, o0, o1, mC, l_run);
        __syncthreads();
    }

    int2v lp = plswap(__float_as_int(l_run), __float_as_int(l_run));
    l_run = __int_as_float(lp[0]) + __int_as_float(lp[1]);

    float (*obuf)[2][64] = (float (*)[2][64])(&lds[0][0][0]);
    float (*mrg)[64][2] = (float (*)[64][2])(&lds[0][0][0] + 16384);
    if (half == 1) {
        mrg[qt][lane][0] = mC;
        mrg[qt][lane][1] = l_run;
#pragma unroll
        for (int e = 0; e < 16; e++) {
            obuf[e][qt][lane] = o0[e];
            obuf[16 + e][qt][lane] = o1[e];
        }
    }
    __syncthreads();
    if (half == 0) {
        const float m2C = mrg[qt][lane][0], l2 = mrg[qt][lane][1];
        const float mm = fmaxf(mC, m2C);
        const float e1 = fexp2(mC - mm);
        const float e2 = fexp2(m2C - mm);
        const float linv = 1.f / (l_run * e1 + l2 * e2);
        bf16_t* Orow = Oa + ((size_t)b * S_SZ + q0 + l31) * D_MODEL + h * HEAD_DIM;
#pragma unroll
        for (int db = 0; db < 2; db++) {
#pragma unroll
            for (int rq = 0; rq < 4; rq++) {
                bf16x4 st;
#pragma unroll
                for (int i = 0; i < 4; i++) {
                    const int e = rq * 4 + i;
                    const float own = db ? o1[e] : o0[e];
                    const float oth = obuf[db * 16 + e][qt][lane];
                    st[i] = (bf16_t)((own * e1 + oth * e2) * linv);
                }
                *(bf16x4*)(Orow + db * 32 + rq * 8 + hi * 4) = st;
            }
        }
    }
}

// ---------------------------------------------------------------------------
// LayerNorm over 1024: A,A2 bf16 split-K partials; R bf16 residual.
// Outputs: optional f32 Xf, optional bf16 Xb.
// ---------------------------------------------------------------------------
__global__ __launch_bounds__(256) void ln_fused(const bf16_t* __restrict__ A,
                                                const bf16_t* __restrict__ A2,
                                                const bf16_t* __restrict__ R,
                                                const float* __restrict__ gamma,
                                                const float* __restrict__ beta,
                                                float* __restrict__ Xf,
                                                bf16_t* __restrict__ Xb) {
    __shared__ float red[8];
    int row = blockIdx.x, tid = threadIdx.x;
    size_t base = (size_t)row * D_MODEL + tid * 4;
    bf16x4 a = *(const bf16x4*)(A + base);
    bf16x4 a2 = *(const bf16x4*)(A2 + base);
    bf16x4 rv = *(const bf16x4*)(R + base);
    float v0 = (float)a[0] + (float)a2[0] + (float)rv[0];
    float v1 = (float)a[1] + (float)a2[1] + (float)rv[1];
    float v2 = (float)a[2] + (float)a2[2] + (float)rv[2];
    float v3 = (float)a[3] + (float)a2[3] + (float)rv[3];
    float s = v0 + v1 + v2 + v3;
    float q = v0 * v0 + v1 * v1 + v2 * v2 + v3 * v3;
#pragma unroll
    for (int off = 32; off; off >>= 1) { s += __shfl_down(s, off); q += __shfl_down(q, off); }
    if ((tid & 63) == 0) { red[tid >> 6] = s; red[4 + (tid >> 6)] = q; }
    __syncthreads();
    s = red[0] + red[1] + red[2] + red[3];
    q = red[4] + red[5] + red[6] + red[7];
    float mean = s * (1.f / D_MODEL);
    float var = q * (1.f / D_MODEL) - mean * mean;
    float rstd = rsqrtf(var + 1e-5f);
    float4 gm = *(const float4*)(gamma + tid * 4);
    float4 bt = *(const float4*)(beta + tid * 4);
    float y0 = (v0 - mean) * rstd * gm.x + bt.x;
    float y1 = (v1 - mean) * rstd * gm.y + bt.y;
    float y2 = (v2 - mean) * rstd * gm.z + bt.z;
    float y3 = (v3 - mean) * rstd * gm.w + bt.w;
    if (Xf) {
        float4 yo; yo.x = y0; yo.y = y1; yo.z = y2; yo.w = y3;
        *(float4*)(Xf + base) = yo;
    }
    if (Xb) {
        bf16x4 ob; ob[0] = (bf16_t)y0; ob[1] = (bf16_t)y1; ob[2] = (bf16_t)y2; ob[3] = (bf16_t)y3;
        *(bf16x4*)(Xb + base) = ob;
    }
}

// ---------------------------------------------------------------------------
extern "C" void kernel_launch(void* const* d_in, const int* in_sizes, int n_in,
                              void* d_out, int out_size, void* d_ws, size_t ws_size,
                              hipStream_t stream) {
    const float* value = (const float*)d_in[0];
    const float* key   = (const float*)d_in[1];
    const float* query = (const float*)d_in[2];
    const float* wq = (const float*)d_in[3];
    const float* bq = (const float*)d_in[4];
    const float* wk = (const float*)d_in[5];
    const float* bk = (const float*)d_in[6];
    const float* wv = (const float*)d_in[7];
    const float* bv = (const float*)d_in[8];
    const float* wo = (const float*)d_in[9];
    const float* bo = (const float*)d_in[10];
    const float* g1 = (const float*)d_in[11];
    const float* beta1 = (const float*)d_in[12];
    const float* w1 = (const float*)d_in[13];
    const float* b1 = (const float*)d_in[14];
    const float* w2 = (const float*)d_in[15];
    const float* b2 = (const float*)d_in[16];
    const float* g2 = (const float*)d_in[17];
    const float* beta2 = (const float*)d_in[18];
    (void)in_sizes; (void)n_in; (void)out_size; (void)ws_size;

    const size_t MB = 1ull << 20;
    char* ws = (char*)d_ws;
    bf16_t* wqT = (bf16_t*)(ws + 0 * MB);
    bf16_t* wkT = (bf16_t*)(ws + 2 * MB);
    bf16_t* wvT = (bf16_t*)(ws + 4 * MB);
    bf16_t* woT = (bf16_t*)(ws + 6 * MB);
    bf16_t* w1T = (bf16_t*)(ws + 8 * MB);
    bf16_t* w2T = (bf16_t*)(ws + 16 * MB);
    bf16_t* q_bf = (bf16_t*)(ws + 24 * MB);  // LIVE until LN1 (residual)
    bf16_t* k_bf = (bf16_t*)(ws + 32 * MB);
    bf16_t* v_bf = (bf16_t*)(ws + 40 * MB);
    bf16_t* Qp  = (bf16_t*)(ws + 48 * MB);
    bf16_t* Kp  = (bf16_t*)(ws + 56 * MB);
    bf16_t* VT  = (bf16_t*)(ws + 64 * MB);   // [B][H][64][S], written by QKV
    bf16_t* attn = (bf16_t*)(ws + 88 * MB);  // q_bf stays live
    bf16_t* woP0 = (bf16_t*)(ws + 32 * MB);  // reuse k_bf (dead after QKV)
    bf16_t* woP1 = (bf16_t*)(ws + 42 * MB);
    bf16_t* x_b = (bf16_t*)(ws + 96 * MB);   // LN1 out, LIVE until LN2 (residual)
    bf16_t* h_b = (bf16_t*)(ws + 32 * MB);   // reuse woP (dead after LN1), 32MB
    bf16_t* ffP0 = (bf16_t*)(ws + 64 * MB);  // reuse VT (dead after flash)
    bf16_t* ffP1 = (bf16_t*)(ws + 72 * MB);

    dim3 blk(256);
    dim3 blk512(512);

    // 1) single prep launch: input casts + all weight transposes
    prep_all<<<24576, blk, 0, stream>>>(query, key, value, q_bf, k_bf, v_bf,
                                        wq, wk, wv, wo, w1, w2,
                                        wqT, wkT, wvT, woT, w1T, w2T);

    // 2) grouped QKV projection; V written directly into VT layout
    gemm_qkv8p<<<dim3(16, 4, 3), blk512, 0, stream>>>(q_bf, k_bf, v_bf, wqT, wkT, wvT,
                                                      bq, bk, bv, Qp, Kp, VT);

    // 3) flash attention v5 (defer-max, 2-buffer ring)
    flash_attn<<<dim3(32, 16, 2), blk, 0, stream>>>(Qp, Kp, VT, attn);

    // 4) WO projection (split-K=2, bf16 partials)
    gemm8p<1, false><<<dim3(16, 8, 2), blk512, 0, stream>>>(attn, 1024, woT, 1024, bo, woP0, woP1, D_MODEL, 512);

    // 5) LN1: x = LN(woP0 + woP1 + q_bf)  [bf16 residual]
    ln_fused<<<4096, blk, 0, stream>>>(woP0, woP1, q_bf, g1, beta1, nullptr, x_b);

    // 6) FF1 + ReLU (BN=256, bf16 out)
    gemm8p_b<2, true><<<dim3(16, 16, 1), blk512, 0, stream>>>(x_b, 1024, w1T, 1024, b1, h_b, FF_DIM, 1024);

    // 7) FF2 (split-K=2, bf16 partials)
    gemm8p<1, false><<<dim3(16, 8, 2), blk512, 0, stream>>>(h_b, 4096, w2T, 4096, b2, ffP0, ffP1, D_MODEL, 2048);

    // 8) LN2 -> d_out (bf16 residual x_b)
    ln_fused<<<4096, blk, 0, stream>>>(ffP0, ffP1, x_b, g2, beta2, (float*)d_out, nullptr);
}